// Round 14
// baseline (16677.704 us; speedup 1.0000x reference)
//
#include <hip/hip_runtime.h>

#define Lnum 2
#define BSn  64
#define Tn   512
#define ECn  1024
#define CA1n 1024
#define CHUNK 16

typedef short bf16x8 __attribute__((ext_vector_type(8)));
typedef float f32x4  __attribute__((ext_vector_type(4)));

#define MFMA16(a,b,c) __builtin_amdgcn_mfma_f32_16x16x32_bf16((a),(b),(c),0,0,0)

// d_out layout: [actCell 64*2][ec3his 2*512*1024][ec5his ...][ca1his ...]
#define OUT_E3  128
#define OUT_E5  (128 + Lnum*Tn*ECn)
#define OUT_CA1 (128 + 2*Lnum*Tn*ECn)

// ws layout (bytes) — IDENTICAL to R12 (proven <= ws_size)
#define WS_FLAGS 0                      // counters, one per 64B line
#define WS_EC3S  8192                   // bf16 [16 slot][2 L][64][1024] = 4MB
#define WS_CA1S  4202496                // bf16 [16 slot][2 L][64][1024] = 4MB
#define WS_EC5F  8396800                // f32 [2][64][1024]
#define WS_EC3F  8921088                // f32 [2][64][1024]
#define WS_CA1L  9445376                // f32 [64][1024]
#define WS_S     9707520                // bf16 [2][512][1024]
#define WS_W1T   11804672               // bf16 [2][1024c][1024k]
#define WS_W2T   15998976               // bf16 [2][1024e][1024k]
#define WS_W3T   20193280               // bf16 [1024e][1024k]  (ends ~22.3MB)

#define AST64(p, v) __hip_atomic_store((p), (v), __ATOMIC_RELAXED, __HIP_MEMORY_SCOPE_AGENT)
#define AADD(p, v) __hip_atomic_fetch_add((p), (v), __ATOMIC_RELAXED, __HIP_MEMORY_SCOPE_AGENT)
#define ALD(p)    __hip_atomic_load((p), __ATOMIC_RELAXED, __HIP_MEMORY_SCOPE_AGENT)
#define ASTU(p, v) __hip_atomic_store((p), (v), __ATOMIC_RELAXED, __HIP_MEMORY_SCOPE_AGENT)

__device__ __forceinline__ float sigm(float x) { return 1.0f / (1.0f + __expf(-x)); }

__device__ __forceinline__ unsigned f2bfu(float f) {
  unsigned u = __float_as_uint(f);
  u += 0x7fffu + ((u >> 16) & 1u);   // RNE
  return u >> 16;
}
__device__ __forceinline__ short f2bf(float f) { return (short)f2bfu(f); }
__device__ __forceinline__ float bf2f(short s) {
  return __uint_as_float(((unsigned)(unsigned short)s) << 16);
}

// ---- epoch counters (agent scope, line-padded; R12-proven mechanics) ----
__device__ __forceinline__ void pollCnt(const unsigned* c, unsigned need) {
  while (ALD(c) < need) __builtin_amdgcn_s_sleep(1);
  __builtin_amdgcn_sched_barrier(0);
  asm volatile("" ::: "memory");
}
__device__ __forceinline__ void pollCnt2(const unsigned* c0, const unsigned* c1,
                                         unsigned need) {
  while ((ALD(c0) < need) | (ALD(c1) < need)) __builtin_amdgcn_s_sleep(1);
  __builtin_amdgcn_sched_barrier(0);
  asm volatile("" ::: "memory");
}
__device__ __forceinline__ void drainSync() {
  asm volatile("s_waitcnt vmcnt(0)" ::: "memory");
  __syncthreads();
}

// ---------------- prep kernels (R4-R12 proven) ----------------

__global__ void prep_state(const float* __restrict__ ec3_last,
                           const float* __restrict__ ec5_last,
                           unsigned* __restrict__ flags, unsigned* __restrict__ ec3su,
                           float* __restrict__ ec5f, float* __restrict__ ec3f) {
  int i = blockIdx.x * blockDim.x + threadIdx.x;   // 512*256 = 131072
  if (i < 2048) flags[i] = 0u;
  float v3 = ec3_last[i];
  ec3f[i] = v3;
  ec5f[i] = ec5_last[i];
  if (i < Lnum * BSn * 512) {      // pack initial ec3 into slot 15
    float lo = ec3_last[2 * i], hi = ec3_last[2 * i + 1];
    ASTU(ec3su + 15 * 65536 + i, f2bfu(lo) | (f2bfu(hi) << 16));
  }
}

// 64x64 LDS tile transpose fp32[k][c] -> bf16[c][k], for W1 (m=0) and W2 (m=1)
__global__ void prep_wt(const float* __restrict__ w1, const float* __restrict__ w2,
                        short* __restrict__ w1t, short* __restrict__ w2t) {
  __shared__ float tile[64][65];
  const int b = blockIdx.x;               // 1024 = 2 mats * 2 layers * 16*16 tiles
  const int m  = b >> 9;
  const int li = (b >> 8) & 1;
  const int kt = (b >> 4) & 15;
  const int ct = b & 15;
  const float* src = (m == 0 ? w1 : w2) + li * (1024 * 1024);
  short* dst = (m == 0 ? w1t : w2t) + li * (1024 * 1024);
#pragma unroll
  for (int i = 0; i < 16; ++i) {
    int idx = threadIdx.x + i * 256;
    int r = idx >> 6, c = idx & 63;
    tile[r][c] = src[(kt * 64 + r) * 1024 + ct * 64 + c];
  }
  __syncthreads();
#pragma unroll
  for (int i = 0; i < 16; ++i) {
    int idx = threadIdx.x + i * 256;
    int c = idx >> 6, r = idx & 63;
    dst[(ct * 64 + c) * 1024 + kt * 64 + r] = f2bf(tile[r][c]);
  }
}

__global__ void prep_w3(const float* __restrict__ inter_w, short* __restrict__ w3t) {
  int i = blockIdx.x * blockDim.x + threadIdx.x;   // 4096*256 = 1048576
  w3t[i] = f2bf(inter_w[i]);                        // layer 0, already [e][k]
}

__global__ void prep_ca3(const float* __restrict__ wca3ca1, short* __restrict__ S) {
  const int t = blockIdx.x >> 1, li = blockIdx.x & 1;
  __shared__ float gauss[192];
  const float stepc = 512.0f / 1023.0f;
  const float tf = (float)t;
  int kmin = (int)floorf((tf - 40.0f) / stepc) - 1; if (kmin < 0) kmin = 0;
  int kmax = (int)ceilf((tf + 40.0f) / stepc) + 1;  if (kmax > 1023) kmax = 1023;
  int nw = kmax - kmin + 1;
  for (int j = threadIdx.x; j < nw; j += 256) {
    float d = (float)(kmin + j) * stepc - tf;
    gauss[j] = __expf(-d * d * 0.02f);
  }
  __syncthreads();
  const float* W = wca3ca1 + li * (1024 * 1024);
  for (int c = threadIdx.x; c < 1024; c += 256) {
    float s = 0.0f;
    for (int j = 0; j < nw; ++j) s += gauss[j] * W[(kmin + j) * 1024 + c];
    S[(li * Tn + t) * 1024 + c] = f2bf(sigm(10.0f * (s - 0.5f)));
  }
}

// ---------------- 16-step chunk kernel, XCD-colocated layers ----------------
// grid 512; blocks with (b&7)>=2 exit. Layer li=b&7 on XCD li: 64 blocks x 16
// cols, 2 blocks/CU. Intra-layer exchange: plain stores -> local L2 -> plain
// loads (each slot line touched once per dispatch => no stale L1/L2). Only
// ca1[0] crosses XCDs: layer-0 re-issues the same packed u64 as an sc1 store
// (identical bytes => benign vs dirty evictions) at phase-B start, publishes
// via cntM after its phase-B drain; layer-1 plain-reads it from IF$.
__global__ void __launch_bounds__(256, 2) stepchunk(
    const float* __restrict__ cue,
    const short* __restrict__ w1t, const short* __restrict__ w2t,
    const short* __restrict__ w3t, const short* __restrict__ stab,
    const float* __restrict__ ca1bias, const float* __restrict__ ec5bias,
    const float* __restrict__ interb,
    unsigned* __restrict__ flags, short* __restrict__ ec3s,
    short* __restrict__ ca1s, float* __restrict__ ec5f, float* __restrict__ ec3f,
    float* __restrict__ ca1l, float* __restrict__ out, int t0) {
  extern __shared__ short lds[];
  const int b = blockIdx.x;
  const int li = b & 7;
  if (li >= Lnum) return;

  short* BT1 = lds;                         // [16c][1024k] swizzled
  short* BT2 = lds + 16 * 1024;
  float* hist = (float*)(lds + 32 * 1024);  // [3][16][16] f32 row-0 history
  short* XP   = lds + 32 * 1024 + 1536;     // [4 wave][256] pack scratch

  unsigned* cntA0 = flags;            // layer-0 A arrivals   (line 0)
  unsigned* cntB0 = flags + 16;       // layer-0 B arrivals   (line 1)
  unsigned* cntA1 = flags + 32;       // layer-1 A arrivals   (line 2)
  unsigned* cntB1 = flags + 48;       // layer-1 B arrivals   (line 3)
  unsigned* cntM  = flags + 64;       // layer-0 sc1-mirror   (line 4)

  const int wid = b >> 3;            // 0..63
  const int c0 = wid << 4;           // 16-column tile
  const int tid = threadIdx.x;
  const int lane = tid & 63, wave = tid >> 6;
  const int fr = lane & 15, ks = lane >> 4;
  const int r0 = wave << 4;
  const int ccol = c0 + fr;
  const int rw = lane >> 2, j = lane & 3;   // packed-u64 row/colgroup
  short* XPw = XP + wave * 256;

  unsigned* myCntA = li ? cntA1 : cntA0;
  unsigned* myCntB = li ? cntB1 : cntB0;

  // ---- stage W1,W2 slices into LDS once per chunk (R12-proven)
  {
    int cp = tid & 15;
    int k0 = (tid >> 4) << 6;
    int xm = (cp & 7) << 3;
    const short* s1 = w1t + li * 1048576 + (c0 + cp) * 1024;
    const short* s2 = w2t + li * 1048576 + (c0 + cp) * 1024;
#pragma unroll
    for (int jj = 0; jj < 8; ++jj) {
      int k = k0 + jj * 8;
      *(bf16x8*)(BT1 + cp * 1024 + (k ^ xm)) = *(const bf16x8*)(s1 + k);
      *(bf16x8*)(BT2 + cp * 1024 + (k ^ xm)) = *(const bf16x8*)(s2 + k);
    }
  }
  __syncthreads();

  const int xsw = (fr & 7) << 3;
  const short* B1 = BT1 + fr * 1024;
  const short* B2 = BT2 + fr * 1024;
  const short* W3 = w3t + ccol * 1024 + ks * 8;   // L2-resident, li==1 only

  const float cb  = ca1bias[li * 1024 + ccol];
  const float e5b = ec5bias[li * 1024 + ccol];
  const float ib0 = interb[1024 + ccol];

  float e5r[4], e3r[4];
#pragma unroll
  for (int r = 0; r < 4; ++r) {
    int sidx = li * 65536 + (r0 + ks * 4 + r) * 1024 + ccol;
    e5r[r] = ec5f[sidx];
    e3r[r] = ec3f[sidx];
  }

  bf16x8 ar[32];
  f32x4 cvv;
  unsigned long long mirv = 0ull;
  int mirIdx = 0;
  unsigned long long* ca1q = (unsigned long long*)ca1s;
  unsigned long long* ec3q = (unsigned long long*)ec3s;

  for (int tt = 0; tt < CHUNK; ++tt) {
    const int t = t0 + tt;
    const int rd = (tt + 15) & 15;

    // ---------- phase A: ca1 = relu(S * (1 + 3*sig(ec3@W1)) - bias) ----------
    {
      if (wave == 0) pollCnt(myCntB, 64u * (unsigned)t);
      __syncthreads();
      const short* A1 = ec3s + ((rd * 2 + li) * 64 + (r0 + fr)) * 1024 + ks * 8;
#pragma unroll
      for (int kk = 0; kk < 16; ++kk) {
        ar[kk]      = *(const bf16x8*)(A1 + kk * 32);
        ar[16 + kk] = *(const bf16x8*)(A1 + 512 + kk * 32);
      }
      __builtin_amdgcn_sched_barrier(0);
      f32x4 a0 = {0.f,0.f,0.f,0.f}, a1 = {0.f,0.f,0.f,0.f};
#pragma unroll
      for (int kk = 0; kk < 16; ++kk) {
        a0 = MFMA16(ar[kk],      *(const bf16x8*)(B1 + ((kk * 32 + ks * 8) ^ xsw)),       a0);
        a1 = MFMA16(ar[16 + kk], *(const bf16x8*)(B1 + ((512 + kk * 32 + ks * 8) ^ xsw)), a1);
      }
      f32x4 acc = a0 + a1;
      const float g = bf2f(stab[(li * Tn + t) * 1024 + ccol]);
#pragma unroll
      for (int r = 0; r < 4; ++r) {
        float cv = fmaxf(g * (1.0f + 3.0f * sigm(acc[r])) - cb, 0.0f);
        cvv[r] = cv;
        XPw[(ks * 4 + r) * 16 + fr] = f2bf(cv);
      }
      if (wave == 0 && ks == 0) hist[tt * 16 + fr] = cvv[0];
      unsigned long long pk = *(const unsigned long long*)(XPw + rw * 16 + j * 4);
      int idx = ((tt * 2 + li) * 64 + r0 + rw) * 256 + (c0 >> 2) + j;
      ca1q[idx] = pk;                       // plain store -> local L2
      if (li == 0) { mirv = pk; mirIdx = idx; }
      drainSync();                          // L2-ack drain (fast)
      if (tid == 0) AADD(myCntA, 1u);
    }

    // ---------- phase B: ec5/ec3 update ----------
    {
      if (li == 0) AST64(ca1q + mirIdx, mirv);   // sc1 dup (same bytes) -> IF$
      float cueq[4];
      if (li == 0) {
#pragma unroll
        for (int r = 0; r < 4; ++r)
          cueq[r] = cue[((r0 + ks * 4 + r) * Tn + t) * 1024 + ccol];
      }
      if (wave == 0) {
        if (li == 0) pollCnt(cntA0, 64u * (unsigned)(t + 1));
        else         pollCnt2(cntA1, cntM, 64u * (unsigned)(t + 1));
      }
      __syncthreads();
      const short* A2 = ca1s + ((tt * 2 + li) * 64 + (r0 + fr)) * 1024 + ks * 8;
#pragma unroll
      for (int kk = 0; kk < 16; ++kk) {
        ar[kk]      = *(const bf16x8*)(A2 + kk * 32);
        ar[16 + kk] = *(const bf16x8*)(A2 + 512 + kk * 32);
      }
      __builtin_amdgcn_sched_barrier(0);
      f32x4 p0 = {0.f,0.f,0.f,0.f}, p1 = {0.f,0.f,0.f,0.f};
#pragma unroll
      for (int kk = 0; kk < 16; ++kk) {
        p0 = MFMA16(ar[kk],      *(const bf16x8*)(B2 + ((kk * 32 + ks * 8) ^ xsw)),       p0);
        p1 = MFMA16(ar[16 + kk], *(const bf16x8*)(B2 + ((512 + kk * 32 + ks * 8) ^ xsw)), p1);
      }
      f32x4 g2 = p0 + p1;

      f32x4 xin;
      if (li == 1) {                        // G3: A = ca1[0] (IF$ via plain), B = W3 (L2)
        const short* A3 = ca1s + ((tt * 2) * 64 + (r0 + fr)) * 1024 + ks * 8;
#pragma unroll
        for (int kk = 0; kk < 16; ++kk) {
          ar[kk]      = *(const bf16x8*)(A3 + kk * 32);
          ar[16 + kk] = *(const bf16x8*)(A3 + 512 + kk * 32);
        }
        __builtin_amdgcn_sched_barrier(0);
        f32x4 q0 = {0.f,0.f,0.f,0.f}, q1 = {0.f,0.f,0.f,0.f};
#pragma unroll
        for (int kk = 0; kk < 16; ++kk) {
          q0 = MFMA16(ar[kk],      *(const bf16x8*)(W3 + kk * 32),       q0);
          q1 = MFMA16(ar[16 + kk], *(const bf16x8*)(W3 + 512 + kk * 32), q1);
        }
        f32x4 q = q0 + q1;
#pragma unroll
        for (int r = 0; r < 4; ++r) xin[r] = q[r] + ib0;
      } else {
#pragma unroll
        for (int r = 0; r < 4; ++r) xin[r] = cueq[r];
      }

#pragma unroll
      for (int r = 0; r < 4; ++r) {
        float raw = e5r[r] + g2[r] + e5b;            // 10*TS == 1.0f exactly
        float e5 = 0.69f + 0.3f * sigm(4.0f * (raw - 0.3f));
        e5r[r] = e5;
        float e3 = e5 * e3r[r] + 0.6f * xin[r];
        e3r[r] = e3;
        XPw[(ks * 4 + r) * 16 + fr] = f2bf(e3);
      }
      if (wave == 0 && ks == 0) {
        hist[256 + tt * 16 + fr] = e5r[0];
        hist[512 + tt * 16 + fr] = e3r[0];
      }
      unsigned long long pk3 = *(const unsigned long long*)(XPw + rw * 16 + j * 4);
      ec3q[((tt * 2 + li) * 64 + r0 + rw) * 256 + (c0 >> 2) + j] = pk3;  // plain
      drainSync();   // covers ec3 plain stores + li0's sc1 mirror
      if (tid == 0) {
        AADD(myCntB, 1u);
        if (li == 0) AADD(cntM, 1u);
      }
    }
  }

  // ---- post-loop (off critical path): history flush, ca1l, state spill ----
  if (wave == 0) {
    for (int s = ks; s < CHUNK; s += 4) {
      int t = t0 + s;
      out[OUT_CA1 + (li * Tn + t) * 1024 + c0 + fr] = hist[s * 16 + fr];
      out[OUT_E5  + (li * Tn + t) * 1024 + c0 + fr] = hist[256 + s * 16 + fr];
      out[OUT_E3  + (li * Tn + t) * 1024 + c0 + fr] = hist[512 + s * 16 + fr];
    }
  }
  if (t0 + CHUNK == Tn && li == 1) {
#pragma unroll
    for (int r = 0; r < 4; ++r)
      ca1l[(r0 + ks * 4 + r) * 1024 + ccol] = cvv[r];
  }
#pragma unroll
  for (int r = 0; r < 4; ++r) {
    int sidx = li * 65536 + (r0 + ks * 4 + r) * 1024 + ccol;
    ec5f[sidx] = e5r[r];
    ec3f[sidx] = e3r[r];
  }
}

__global__ void act_cell(const float* __restrict__ ca1l, const float* __restrict__ wca1act,
                         const float* __restrict__ actbias, float* __restrict__ out) {
  int tid = threadIdx.x;
  if (tid < 128) {
    int b = tid >> 1, a = tid & 1;
    float s = 0.0f;
    for (int k = 0; k < 1024; ++k) s += ca1l[b * 1024 + k] * wca1act[k * 2 + a];
    out[b * 2 + a] = s + actbias[a];
  }
}

extern "C" void kernel_launch(void* const* d_in, const int* in_sizes, int n_in,
                              void* d_out, int out_size, void* d_ws, size_t ws_size,
                              hipStream_t stream) {
  (void)in_sizes; (void)n_in; (void)out_size; (void)ws_size;
  const float* cue      = (const float*)d_in[0];
  const float* ec3_last = (const float*)d_in[1];
  const float* ec5_last = (const float*)d_in[2];
  const float* wca3ca1  = (const float*)d_in[4];
  const float* wec3ca1  = (const float*)d_in[5];
  const float* wca1ec5  = (const float*)d_in[6];
  const float* ca1bias  = (const float*)d_in[7];
  const float* ec5bias  = (const float*)d_in[8];
  const float* inter_w  = (const float*)d_in[9];
  const float* inter_b  = (const float*)d_in[10];
  const float* wca1act  = (const float*)d_in[11];
  const float* actbias  = (const float*)d_in[12];
  float* out = (float*)d_out;

  char* ws = (char*)d_ws;
  unsigned* flags = (unsigned*)(ws + WS_FLAGS);
  short* ec3s = (short*)(ws + WS_EC3S);
  short* ca1s = (short*)(ws + WS_CA1S);
  float* ec5f = (float*)(ws + WS_EC5F);
  float* ec3f = (float*)(ws + WS_EC3F);
  float* ca1l = (float*)(ws + WS_CA1L);
  short* stab = (short*)(ws + WS_S);
  short* w1t  = (short*)(ws + WS_W1T);
  short* w2t  = (short*)(ws + WS_W2T);
  short* w3t  = (short*)(ws + WS_W3T);

  prep_state<<<dim3(512), dim3(256), 0, stream>>>(ec3_last, ec5_last, flags,
                                                  (unsigned*)ec3s, ec5f, ec3f);
  prep_wt<<<dim3(1024), dim3(256), 0, stream>>>(wec3ca1, wca1ec5, w1t, w2t);
  prep_w3<<<dim3(4096), dim3(256), 0, stream>>>(inter_w, w3t);
  prep_ca3<<<dim3(1024), dim3(256), 0, stream>>>(wca3ca1, stab);

  hipFuncSetAttribute((const void*)stepchunk,
                      hipFuncAttributeMaxDynamicSharedMemorySize, 70656);

  for (int c = 0; c < Tn / CHUNK; ++c) {
    stepchunk<<<dim3(512), dim3(256), 70656, stream>>>(
        cue, w1t, w2t, w3t, stab, ca1bias, ec5bias, inter_b,
        flags, ec3s, ca1s, ec5f, ec3f, ca1l, out, c * CHUNK);
  }

  act_cell<<<dim3(1), dim3(128), 0, stream>>>(ca1l, wca1act, actbias, out);
}

// Round 17
// 8084.692 us; speedup vs baseline: 2.0629x; 2.0629x over previous
//
#include <hip/hip_runtime.h>

#define Lnum 2
#define BSn  64
#define Tn   512
#define ECn  1024
#define CA1n 1024
#define CHUNK 16

typedef short bf16x8 __attribute__((ext_vector_type(8)));
typedef float f32x4  __attribute__((ext_vector_type(4)));

#define MFMA16(a,b,c) __builtin_amdgcn_mfma_f32_16x16x32_bf16((a),(b),(c),0,0,0)

// d_out layout: [actCell 64*2][ec3his 2*512*1024][ec5his ...][ca1his ...]
#define OUT_E3  128
#define OUT_E5  (128 + Lnum*Tn*ECn)
#define OUT_CA1 (128 + 2*Lnum*Tn*ECn)

// ws layout (bytes) — IDENTICAL to R12 (proven <= ws_size)
#define WS_FLAGS 0                      // counters, one per 64B line
#define WS_EC3S  8192                   // bf16 [16 slot][2 L][64][1024] = 4MB
#define WS_CA1S  4202496                // bf16 [16 slot][2 L][64][1024] = 4MB
#define WS_EC5F  8396800                // f32 [2][64][1024]
#define WS_EC3F  8921088                // f32 [2][64][1024]
#define WS_CA1L  9445376                // f32 [64][1024]
#define WS_S     9707520                // bf16 [2][512][1024]
#define WS_W1T   11804672               // bf16 [2][1024c][1024k]
#define WS_W2T   15998976               // bf16 [2][1024e][1024k]
#define WS_W3T   20193280               // bf16 [1024e][1024k]  (ends ~22.3MB)

#define AST(p, v) __hip_atomic_store((p), (v), __ATOMIC_RELAXED, __HIP_MEMORY_SCOPE_AGENT)
#define AADD(p, v) __hip_atomic_fetch_add((p), (v), __ATOMIC_RELAXED, __HIP_MEMORY_SCOPE_AGENT)
#define ALD(p)    __hip_atomic_load((p), __ATOMIC_RELAXED, __HIP_MEMORY_SCOPE_AGENT)

__device__ __forceinline__ float sigm(float x) { return 1.0f / (1.0f + __expf(-x)); }

__device__ __forceinline__ unsigned f2bfu(float f) {
  unsigned u = __float_as_uint(f);
  u += 0x7fffu + ((u >> 16) & 1u);   // RNE
  return u >> 16;
}
__device__ __forceinline__ short f2bf(float f) { return (short)f2bfu(f); }
__device__ __forceinline__ float bf2f(short s) {
  return __uint_as_float(((unsigned)(unsigned short)s) << 16);
}

// ---- epoch-counter sync (R12-proven): 4 line-padded counters ----
__device__ __forceinline__ void pollCnt(const unsigned* c, unsigned need) {
  while (ALD(c) < need) __builtin_amdgcn_s_sleep(1);
  __builtin_amdgcn_sched_barrier(0);
  asm volatile("" ::: "memory");
}
__device__ __forceinline__ void pollCnt2(const unsigned* c0, const unsigned* c1,
                                         unsigned need) {
  while ((ALD(c0) < need) | (ALD(c1) < need)) __builtin_amdgcn_s_sleep(1);
  __builtin_amdgcn_sched_barrier(0);
  asm volatile("" ::: "memory");
}
// Publish: drain own sc1 slot stores, then tid0 bumps the epoch counter.
__device__ __forceinline__ void publish(unsigned* c) {
  asm volatile("s_waitcnt vmcnt(0)" ::: "memory");
  __syncthreads();
  if (threadIdx.x == 0)
    __hip_atomic_fetch_add(c, 1u, __ATOMIC_RELAXED, __HIP_MEMORY_SCOPE_AGENT);
}

// ---------------- prep kernels (R4-R12 proven) ----------------

__global__ void prep_state(const float* __restrict__ ec3_last,
                           const float* __restrict__ ec5_last,
                           unsigned* __restrict__ flags, unsigned* __restrict__ ec3su,
                           float* __restrict__ ec5f, float* __restrict__ ec3f) {
  int i = blockIdx.x * blockDim.x + threadIdx.x;   // 512*256 = 131072
  if (i < 2048) flags[i] = 0u;
  float v3 = ec3_last[i];
  ec3f[i] = v3;
  ec5f[i] = ec5_last[i];
  if (i < Lnum * BSn * 512) {      // pack initial ec3 into slot 15
    float lo = ec3_last[2 * i], hi = ec3_last[2 * i + 1];
    AST(ec3su + 15 * 65536 + i, f2bfu(lo) | (f2bfu(hi) << 16));
  }
}

// 64x64 LDS tile transpose fp32[k][c] -> bf16[c][k], for W1 (m=0) and W2 (m=1)
__global__ void prep_wt(const float* __restrict__ w1, const float* __restrict__ w2,
                        short* __restrict__ w1t, short* __restrict__ w2t) {
  __shared__ float tile[64][65];
  const int b = blockIdx.x;               // 1024 = 2 mats * 2 layers * 16*16 tiles
  const int m  = b >> 9;
  const int li = (b >> 8) & 1;
  const int kt = (b >> 4) & 15;
  const int ct = b & 15;
  const float* src = (m == 0 ? w1 : w2) + li * (1024 * 1024);
  short* dst = (m == 0 ? w1t : w2t) + li * (1024 * 1024);
#pragma unroll
  for (int i = 0; i < 16; ++i) {
    int idx = threadIdx.x + i * 256;
    int r = idx >> 6, c = idx & 63;
    tile[r][c] = src[(kt * 64 + r) * 1024 + ct * 64 + c];
  }
  __syncthreads();
#pragma unroll
  for (int i = 0; i < 16; ++i) {
    int idx = threadIdx.x + i * 256;
    int c = idx >> 6, r = idx & 63;
    dst[(ct * 64 + c) * 1024 + kt * 64 + r] = f2bf(tile[r][c]);
  }
}

__global__ void prep_w3(const float* __restrict__ inter_w, short* __restrict__ w3t) {
  int i = blockIdx.x * blockDim.x + threadIdx.x;   // 4096*256 = 1048576
  w3t[i] = f2bf(inter_w[i]);                        // layer 0, already [e][k]
}

__global__ void prep_ca3(const float* __restrict__ wca3ca1, short* __restrict__ S) {
  const int t = blockIdx.x >> 1, li = blockIdx.x & 1;
  __shared__ float gauss[192];
  const float stepc = 512.0f / 1023.0f;
  const float tf = (float)t;
  int kmin = (int)floorf((tf - 40.0f) / stepc) - 1; if (kmin < 0) kmin = 0;
  int kmax = (int)ceilf((tf + 40.0f) / stepc) + 1;  if (kmax > 1023) kmax = 1023;
  int nw = kmax - kmin + 1;
  for (int j = threadIdx.x; j < nw; j += 256) {
    float d = (float)(kmin + j) * stepc - tf;
    gauss[j] = __expf(-d * d * 0.02f);
  }
  __syncthreads();
  const float* W = wca3ca1 + li * (1024 * 1024);
  for (int c = threadIdx.x; c < 1024; c += 256) {
    float s = 0.0f;
    for (int j = 0; j < nw; ++j) s += gauss[j] * W[(kmin + j) * 1024 + c];
    S[(li * Tn + t) * 1024 + c] = f2bf(sigm(10.0f * (s - 0.5f)));
  }
}

// ---------------- 16-step chunk kernel (R12 base + tail-shaving) ------------
// grid 128, block 256 = 4 waves. XCD-segregated layers (li = b&1). Epoch
// counters. Tail-shaving vs R12: (1) stab + cue prefetched at step top, before
// the polls; (2) history staged in LDS, flushed post-loop (no plain global
// stores inside the step loop polluting the vmcnt(0) drains).
__global__ void __launch_bounds__(256, 1) stepchunk(
    const float* __restrict__ cue,
    const short* __restrict__ w1t, const short* __restrict__ w2t,
    const short* __restrict__ w3t, const short* __restrict__ stab,
    const float* __restrict__ ca1bias, const float* __restrict__ ec5bias,
    const float* __restrict__ interb,
    unsigned* __restrict__ flags, short* __restrict__ ec3s,
    short* __restrict__ ca1s, float* __restrict__ ec5f, float* __restrict__ ec3f,
    float* __restrict__ ca1l, float* __restrict__ out, int t0) {
  extern __shared__ short lds[];
  short* BT1 = lds;             // [16c][1024k] swizzled: idx = c*1024 + (k ^ ((c&7)<<3))
  short* BT2 = lds + 16 * 1024;
  short* BT3 = lds + 32 * 1024;
  float* hist = (float*)(lds + 48 * 1024);  // [3][16][16] row-0 history

  unsigned* cntA0 = flags;            // layer-0 phase-A arrivals (line 0)
  unsigned* cntA1 = flags + 16;       // layer-1 phase-A arrivals (line 1)
  unsigned* cntB0 = flags + 32;       // layer-0 phase-B arrivals (line 2)
  unsigned* cntB1 = flags + 48;       // layer-1 phase-B arrivals (line 3)
  unsigned* ec3su = (unsigned*)ec3s;
  unsigned* ca1su = (unsigned*)ca1s;

  const int b = blockIdx.x;
  const int li = b & 1;              // XCD-segregated layer mapping
  const int c0 = (b >> 1) << 4;      // column tile start (16 cols)
  const int tid = threadIdx.x;
  const int lane = tid & 63, wave = tid >> 6;
  const int fr = lane & 15, ks = lane >> 4;
  const int r0 = wave << 4;
  const int ccol = c0 + fr;

  unsigned* myCntA = li ? cntA1 : cntA0;
  unsigned* myCntB = li ? cntB1 : cntB0;

  // ---- stage weight slices into LDS once per chunk
  {
    int cp = tid & 15;
    int k0 = (tid >> 4) << 6;
    int xm = (cp & 7) << 3;
    const short* s1 = w1t + li * 1048576 + (c0 + cp) * 1024;
    const short* s2 = w2t + li * 1048576 + (c0 + cp) * 1024;
#pragma unroll
    for (int j = 0; j < 8; ++j) {
      int k = k0 + j * 8;
      *(bf16x8*)(BT1 + cp * 1024 + (k ^ xm)) = *(const bf16x8*)(s1 + k);
      *(bf16x8*)(BT2 + cp * 1024 + (k ^ xm)) = *(const bf16x8*)(s2 + k);
    }
    if (li == 1) {
      const short* s3 = w3t + (c0 + cp) * 1024;
#pragma unroll
      for (int j = 0; j < 8; ++j) {
        int k = k0 + j * 8;
        *(bf16x8*)(BT3 + cp * 1024 + (k ^ xm)) = *(const bf16x8*)(s3 + k);
      }
    }
  }
  __syncthreads();

  const int xsw = (fr & 7) << 3;
  const short* B1 = BT1 + fr * 1024;
  const short* B2 = BT2 + fr * 1024;
  const short* B3 = BT3 + fr * 1024;

  const float cb  = ca1bias[li * 1024 + ccol];
  const float e5b = ec5bias[li * 1024 + ccol];
  const float ib0 = interb[1024 + ccol];    // layer-1 inter_b (used when li==1)

  // block-exclusive fp32 state -> registers for the chunk
  float e5r[4], e3r[4];
#pragma unroll
  for (int r = 0; r < 4; ++r) {
    int sidx = li * 65536 + (r0 + ks * 4 + r) * 1024 + ccol;
    e5r[r] = ec5f[sidx];
    e3r[r] = ec3f[sidx];
  }

  bf16x8 ar[32], ar3[32];
  f32x4 cvv;

  for (int tt = 0; tt < CHUNK; ++tt) {
    const int t = t0 + tt;
    const int rd = (tt + 15) & 15;   // ec3 slot written last step (15 = initial/prev)

    // ---- early read-only prefetches: issue before any poll, consume later ----
    const float g = bf2f(stab[(li * Tn + t) * 1024 + ccol]);
    float cueq[4];
    if (li == 0) {
#pragma unroll
      for (int r = 0; r < 4; ++r)
        cueq[r] = cue[((r0 + ks * 4 + r) * Tn + t) * 1024 + ccol];
    }

    // ---------- phase A: ca1 = relu(S * (1 + 3*sig(ec3@W1)) - bias) ----------
    {
      if (wave == 0) pollCnt(myCntB, 64u * (unsigned)t);   // own layer ec3[t-1]
      __syncthreads();
      const short* A1 = ec3s + ((rd * 2 + li) * 64 + (r0 + fr)) * 1024 + ks * 8;
#pragma unroll
      for (int kk = 0; kk < 16; ++kk) {
        ar[kk]      = *(const bf16x8*)(A1 + kk * 32);
        ar[16 + kk] = *(const bf16x8*)(A1 + 512 + kk * 32);
      }
      __builtin_amdgcn_sched_barrier(0);   // bulk-issue all 32 loads first
      f32x4 a0 = {0.f,0.f,0.f,0.f}, a1 = {0.f,0.f,0.f,0.f};
#pragma unroll
      for (int kk = 0; kk < 16; ++kk) {
        a0 = MFMA16(ar[kk],      *(const bf16x8*)(B1 + ((kk * 32 + ks * 8) ^ xsw)),       a0);
        a1 = MFMA16(ar[16 + kk], *(const bf16x8*)(B1 + ((512 + kk * 32 + ks * 8) ^ xsw)), a1);
      }
      f32x4 acc = a0 + a1;
#pragma unroll
      for (int r = 0; r < 4; ++r) {
        int grow = r0 + ks * 4 + r;
        float cv = fmaxf(g * (1.0f + 3.0f * sigm(acc[r])) - cb, 0.0f);
        cvv[r] = cv;
        unsigned my = f2bfu(cv);
        unsigned pr = (unsigned)__shfl_xor((int)my, 1);
        if ((fr & 1) == 0)
          AST(ca1su + ((tt * 2 + li) * 64 + grow) * 512 + ((c0 + fr) >> 1), my | (pr << 16));
      }
      if (wave == 0 && ks == 0) hist[tt * 16 + fr] = cvv[0];   // LDS history
      publish(myCntA);                     // drain covers ONLY slot stores
      if (t == Tn - 1 && li == 1) {        // once per run, off critical path
#pragma unroll
        for (int r = 0; r < 4; ++r)
          ca1l[(r0 + ks * 4 + r) * 1024 + ccol] = cvv[r];
      }
    }

    // ---------- phase B: ec5/ec3 update ----------
    {
      if (wave == 0) {
        if (li == 0) pollCnt(cntA0, 64u * (unsigned)(t + 1));
        else         pollCnt2(cntA0, cntA1, 64u * (unsigned)(t + 1));
      }
      __syncthreads();
      const short* A2 = ca1s + ((tt * 2 + li) * 64 + (r0 + fr)) * 1024 + ks * 8;
#pragma unroll
      for (int kk = 0; kk < 16; ++kk) {
        ar[kk]      = *(const bf16x8*)(A2 + kk * 32);
        ar[16 + kk] = *(const bf16x8*)(A2 + 512 + kk * 32);
      }
      if (li == 1) {                       // also bulk-issue the G3 panel loads
        const short* A3 = ca1s + ((tt * 2) * 64 + (r0 + fr)) * 1024 + ks * 8;
#pragma unroll
        for (int kk = 0; kk < 16; ++kk) {
          ar3[kk]      = *(const bf16x8*)(A3 + kk * 32);
          ar3[16 + kk] = *(const bf16x8*)(A3 + 512 + kk * 32);
        }
      }
      __builtin_amdgcn_sched_barrier(0);
      f32x4 p0 = {0.f,0.f,0.f,0.f}, p1 = {0.f,0.f,0.f,0.f};
#pragma unroll
      for (int kk = 0; kk < 16; ++kk) {
        p0 = MFMA16(ar[kk],      *(const bf16x8*)(B2 + ((kk * 32 + ks * 8) ^ xsw)),       p0);
        p1 = MFMA16(ar[16 + kk], *(const bf16x8*)(B2 + ((512 + kk * 32 + ks * 8) ^ xsw)), p1);
      }
      f32x4 g2 = p0 + p1;

      f32x4 xin;
      if (li == 1) {
        f32x4 q0 = {0.f,0.f,0.f,0.f}, q1 = {0.f,0.f,0.f,0.f};
#pragma unroll
        for (int kk = 0; kk < 16; ++kk) {
          q0 = MFMA16(ar3[kk],      *(const bf16x8*)(B3 + ((kk * 32 + ks * 8) ^ xsw)),       q0);
          q1 = MFMA16(ar3[16 + kk], *(const bf16x8*)(B3 + ((512 + kk * 32 + ks * 8) ^ xsw)), q1);
        }
        f32x4 q = q0 + q1;
#pragma unroll
        for (int r = 0; r < 4; ++r) xin[r] = q[r] + ib0;
      } else {
#pragma unroll
        for (int r = 0; r < 4; ++r) xin[r] = cueq[r];
      }

#pragma unroll
      for (int r = 0; r < 4; ++r) {
        float raw = e5r[r] + g2[r] + e5b;            // 10*TS == 1.0f exactly
        float e5 = 0.69f + 0.3f * sigm(4.0f * (raw - 0.3f));
        e5r[r] = e5;
        float e3 = e5 * e3r[r] + 0.6f * xin[r];
        e3r[r] = e3;
        int grow = r0 + ks * 4 + r;
        unsigned my = f2bfu(e3);
        unsigned pr = (unsigned)__shfl_xor((int)my, 1);
        if ((fr & 1) == 0)
          AST(ec3su + ((tt * 2 + li) * 64 + grow) * 512 + ((c0 + fr) >> 1), my | (pr << 16));
      }
      if (wave == 0 && ks == 0) {          // LDS history
        hist[256 + tt * 16 + fr] = e5r[0];
        hist[512 + tt * 16 + fr] = e3r[0];
      }
      publish(myCntB);                     // drain covers ONLY slot stores
    }
  }

  // ---- post-loop: history flush + fp32 state spill (dispatch boundary) ----
  if (wave == 0) {
    for (int s = ks; s < CHUNK; s += 4) {
      int t = t0 + s;
      out[OUT_CA1 + (li * Tn + t) * 1024 + ccol] = hist[s * 16 + fr];
      out[OUT_E5  + (li * Tn + t) * 1024 + ccol] = hist[256 + s * 16 + fr];
      out[OUT_E3  + (li * Tn + t) * 1024 + ccol] = hist[512 + s * 16 + fr];
    }
  }
#pragma unroll
  for (int r = 0; r < 4; ++r) {
    int sidx = li * 65536 + (r0 + ks * 4 + r) * 1024 + ccol;
    ec5f[sidx] = e5r[r];
    ec3f[sidx] = e3r[r];
  }
}

__global__ void act_cell(const float* __restrict__ ca1l, const float* __restrict__ wca1act,
                         const float* __restrict__ actbias, float* __restrict__ out) {
  int tid = threadIdx.x;
  if (tid < 128) {
    int b = tid >> 1, a = tid & 1;
    float s = 0.0f;
    for (int k = 0; k < 1024; ++k) s += ca1l[b * 1024 + k] * wca1act[k * 2 + a];
    out[b * 2 + a] = s + actbias[a];
  }
}

extern "C" void kernel_launch(void* const* d_in, const int* in_sizes, int n_in,
                              void* d_out, int out_size, void* d_ws, size_t ws_size,
                              hipStream_t stream) {
  (void)in_sizes; (void)n_in; (void)out_size; (void)ws_size;
  const float* cue      = (const float*)d_in[0];
  const float* ec3_last = (const float*)d_in[1];
  const float* ec5_last = (const float*)d_in[2];
  const float* wca3ca1  = (const float*)d_in[4];
  const float* wec3ca1  = (const float*)d_in[5];
  const float* wca1ec5  = (const float*)d_in[6];
  const float* ca1bias  = (const float*)d_in[7];
  const float* ec5bias  = (const float*)d_in[8];
  const float* inter_w  = (const float*)d_in[9];
  const float* inter_b  = (const float*)d_in[10];
  const float* wca1act  = (const float*)d_in[11];
  const float* actbias  = (const float*)d_in[12];
  float* out = (float*)d_out;

  char* ws = (char*)d_ws;
  unsigned* flags = (unsigned*)(ws + WS_FLAGS);
  short* ec3s = (short*)(ws + WS_EC3S);
  short* ca1s = (short*)(ws + WS_CA1S);
  float* ec5f = (float*)(ws + WS_EC5F);
  float* ec3f = (float*)(ws + WS_EC3F);
  float* ca1l = (float*)(ws + WS_CA1L);
  short* stab = (short*)(ws + WS_S);
  short* w1t  = (short*)(ws + WS_W1T);
  short* w2t  = (short*)(ws + WS_W2T);
  short* w3t  = (short*)(ws + WS_W3T);

  prep_state<<<dim3(512), dim3(256), 0, stream>>>(ec3_last, ec5_last, flags,
                                                  (unsigned*)ec3s, ec5f, ec3f);
  prep_wt<<<dim3(1024), dim3(256), 0, stream>>>(wec3ca1, wca1ec5, w1t, w2t);
  prep_w3<<<dim3(4096), dim3(256), 0, stream>>>(inter_w, w3t);
  prep_ca3<<<dim3(1024), dim3(256), 0, stream>>>(wca3ca1, stab);

  hipFuncSetAttribute((const void*)stepchunk,
                      hipFuncAttributeMaxDynamicSharedMemorySize, 101376);

  for (int c = 0; c < Tn / CHUNK; ++c) {
    stepchunk<<<dim3(128), dim3(256), 101376, stream>>>(
        cue, w1t, w2t, w3t, stab, ca1bias, ec5bias, inter_b,
        flags, ec3s, ca1s, ec5f, ec3f, ca1l, out, c * CHUNK);
  }

  act_cell<<<dim3(1), dim3(128), 0, stream>>>(ca1l, wca1act, actbias, out);
}